// Round 3
// baseline (827.831 us; speedup 1.0000x reference)
//
#include <hip/hip_runtime.h>
#include <math.h>

#define BB 1024
#define TT 512
#define L2E 1.4426950408889634f

typedef __attribute__((ext_vector_type(8))) short  short8;
typedef __attribute__((ext_vector_type(4))) int    int4v;
typedef __attribute__((ext_vector_type(4))) float  floatx4;

__device__ __forceinline__ float fast_rcp(float x){ return __builtin_amdgcn_rcpf(x); }
__device__ __forceinline__ float exp2f_(float x){ return __builtin_amdgcn_exp2f(x); }
__device__ __forceinline__ float sigmoidf_(float x){ return fast_rcp(1.0f + __expf(-x)); }
__device__ __forceinline__ unsigned bfround(float f){
    unsigned u = __builtin_bit_cast(unsigned, f);
    return u + 0x7fffu + ((u >> 16) & 1u);
}
__device__ __forceinline__ unsigned short f2bf(float f){ return (unsigned short)(bfround(f) >> 16); }
__device__ __forceinline__ float bf2f(unsigned short u){
    return __builtin_bit_cast(float, ((unsigned)u) << 16);
}
// pack two f32 into one u32 of bf16s: lo16 = bf(lo), hi16 = bf(hi)
__device__ __forceinline__ int pack_bf(float lo, float hi){
    return (int)((bfround(lo) >> 16) | (bfround(hi) & 0xffff0000u));
}

// ---------------------------------------------------------------------------
// Swapped-operand biGRU recurrence, zero-LDS.
// Compute G[gate][b] = mfma(A = W-frag, B = h-frag, C = bias-vec):
//   A-frag lane l: W[gc = gtile*16 + (l&15)][k = (l>>4)*8 + j]  (same data as
//     the old B-frag — A/B fragment layouts are element-set identical)
//   B-frag lane l: h[b = l&15][i = (l>>4)*8 + j]               ("ah")
//   D lane l:      G[gc = gtile*16 + (l>>4)*4 + reg][b = l&15]
// After the gate update, lane (c,q) holds h_t for b=c, i in {4q..4q+3} and
// {16+4q..19+4q}. Re-slot to the next step's B-frag (i = 8q'..8q'+7, same b)
// with 8 ds_bpermute + 4 cndmask: no __shared__, no barriers, no lgkm drains.
// r/z reciprocals folded into one rcp. Biases ride in the MFMA C operand.
// ---------------------------------------------------------------------------
__global__ __launch_bounds__(64, 1) void gru_l0(
    const float* __restrict__ x,      // (B,T,4) f32
    const float* __restrict__ w_ih,   // (2,96,4)
    const float* __restrict__ w_hh,   // (2,96,32)
    const float* __restrict__ b_ih,   // (2,96)
    const float* __restrict__ b_hh,   // (2,96)
    unsigned short* __restrict__ h1)  // (B,T,64) bf16
{
    const int tile = blockIdx.x;      // 0..127
    const int bt   = tile >> 1;
    const int d    = tile & 1;
    const int b0   = bt * 16;
    const int L    = threadIdx.x & 63;
    const int c    = L & 15;
    const int q    = L >> 4;

    // weight A-fragments (identical data/indexing to the old B-fragments)
    short8 whh[3][2], wih[3][2];
    #pragma unroll
    for (int g = 0; g < 3; ++g){
        const float sc = (g == 2) ? (2.0f * L2E) : L2E;
        #pragma unroll
        for (int gt = 0; gt < 2; ++gt){
            const int row = d*96 + g*32 + gt*16 + c;
            short8 f;
            #pragma unroll
            for (int j = 0; j < 8; ++j) f[j] = f2bf(w_hh[(size_t)row*32 + q*8 + j] * sc);
            whh[g][gt] = f;
            short8 fi = {0,0,0,0,0,0,0,0};
            if (q == 0){
                #pragma unroll
                for (int j = 0; j < 4; ++j) fi[j] = f2bf(w_ih[(size_t)row*4 + j] * sc);
            }
            wih[g][gt] = fi;
        }
    }
    // biases as per-reg C vectors: reg r of gtile gt sits at gc = gt*16+q*4+r
    floatx4 cbr[2], cbz[2], cbni[2], cbhn[2];
    #pragma unroll
    for (int gt = 0; gt < 2; ++gt){
        #pragma unroll
        for (int r = 0; r < 4; ++r){
            const int gidx = d*96 + gt*16 + q*4 + r;
            cbr[gt][r]  = L2E * (b_ih[gidx]      + b_hh[gidx]);
            cbz[gt][r]  = L2E * (b_ih[gidx + 32] + b_hh[gidx + 32]);
            cbni[gt][r] = 2.0f * L2E * b_ih[gidx + 64];
            cbhn[gt][r] = 2.0f * L2E * b_hh[gidx + 64];
        }
    }

    float hr[2][4] = {{0.f,0.f,0.f,0.f},{0.f,0.f,0.f,0.f}};
    short8 ah = {0,0,0,0,0,0,0,0};   // h_{-1} = 0 (B-frag)

    // bpermute source lanes for the D->B re-slot
    const int addrA = 4 * (c + 32 * (q & 1));   // src quad 2*(q&1)
    const int addrB = addrA + 64;               // src quad 2*(q&1)+1
    const bool selLo = (q < 2);                 // use P0/P1 (i<16) vs P2/P3

    const size_t xrow = (size_t)(b0 + c) * TT;
    float4 xc = {0,0,0,0}, xn1 = {0,0,0,0};
    if (q == 0){
        xc  = *(const float4*)(x + (xrow + (d ? TT-1 : 0))*4);
        xn1 = *(const float4*)(x + (xrow + (d ? TT-2 : 1))*4);
    }

    #pragma unroll 2
    for (int t = 0; t < TT; ++t){
        short8 ax = {0,0,0,0,0,0,0,0};
        if (q == 0){ ax[0]=f2bf(xc.x); ax[1]=f2bf(xc.y); ax[2]=f2bf(xc.z); ax[3]=f2bf(xc.w); }

        floatx4 racc[2], zacc[2], xnacc[2], hnacc[2];
        // x-side (no ah dependence)
        #pragma unroll
        for (int gt = 0; gt < 2; ++gt){
            racc[gt]  = __builtin_amdgcn_mfma_f32_16x16x32_bf16(wih[0][gt], ax, cbr[gt], 0, 0, 0);
            zacc[gt]  = __builtin_amdgcn_mfma_f32_16x16x32_bf16(wih[1][gt], ax, cbz[gt], 0, 0, 0);
            xnacc[gt] = __builtin_amdgcn_mfma_f32_16x16x32_bf16(wih[2][gt], ax, cbni[gt], 0, 0, 0);
        }
        // h-side
        #pragma unroll
        for (int gt = 0; gt < 2; ++gt){
            racc[gt]  = __builtin_amdgcn_mfma_f32_16x16x32_bf16(whh[0][gt], ah, racc[gt], 0, 0, 0);
            zacc[gt]  = __builtin_amdgcn_mfma_f32_16x16x32_bf16(whh[1][gt], ah, zacc[gt], 0, 0, 0);
            hnacc[gt] = __builtin_amdgcn_mfma_f32_16x16x32_bf16(whh[2][gt], ah, cbhn[gt], 0, 0, 0);
        }

        // store h_{t-1} (== ah, B-frag == store layout)
        if (t > 0){
            const int txp = d ? (TT - t) : (t - 1);
            *(short8*)(&h1[((size_t)(b0 + c)*TT + txp)*64 + d*32 + q*8]) = ah;
        }
        // prefetch x for t+2
        float4 xn2 = xn1;
        if (q == 0 && t + 2 < TT)
            xn2 = *(const float4*)(x + (xrow + (d ? TT-3-t : t+2))*4);

        // gate update: lane (c,q), reg (gt,r) -> b=c, i = gt*16 + q*4 + r
        #pragma unroll
        for (int gt = 0; gt < 2; ++gt){
            #pragma unroll
            for (int r = 0; r < 4; ++r){
                const float p  = 1.0f + exp2f_(-racc[gt][r]);
                const float qd = 1.0f + exp2f_(-zacc[gt][r]);
                const float s  = fast_rcp(p * qd);
                const float rg = s * qd;
                const float zg = s * p;
                const float e2 = exp2f_(xnacc[gt][r] + rg * hnacc[gt][r]);
                const float ng = 1.0f - 2.0f * fast_rcp(e2 + 1.0f);
                hr[gt][r] = ng + zg * (hr[gt][r] - ng);
            }
        }
        // pack + cross-quad re-slot into next step's B-frag
        const int P0 = pack_bf(hr[0][0], hr[0][1]);   // i = 4q, 4q+1
        const int P1 = pack_bf(hr[0][2], hr[0][3]);   // i = 4q+2, 4q+3
        const int P2 = pack_bf(hr[1][0], hr[1][1]);   // i = 16+4q, 16+4q+1
        const int P3 = pack_bf(hr[1][2], hr[1][3]);   // i = 16+4q+2, 16+4q+3
        const int tA0 = __builtin_amdgcn_ds_bpermute(addrA, P0);
        const int tA1 = __builtin_amdgcn_ds_bpermute(addrA, P1);
        const int tA2 = __builtin_amdgcn_ds_bpermute(addrA, P2);
        const int tA3 = __builtin_amdgcn_ds_bpermute(addrA, P3);
        const int tB0 = __builtin_amdgcn_ds_bpermute(addrB, P0);
        const int tB1 = __builtin_amdgcn_ds_bpermute(addrB, P1);
        const int tB2 = __builtin_amdgcn_ds_bpermute(addrB, P2);
        const int tB3 = __builtin_amdgcn_ds_bpermute(addrB, P3);
        int4v R;
        R[0] = selLo ? tA0 : tA2;
        R[1] = selLo ? tA1 : tA3;
        R[2] = selLo ? tB0 : tB2;
        R[3] = selLo ? tB1 : tB3;
        ah = __builtin_bit_cast(short8, R);

        xc = xn1; xn1 = xn2;
    }
    // epilogue: ah holds h_{TT-1} in store layout
    {
        const int txl = d ? 0 : TT-1;
        *(short8*)(&h1[((size_t)(b0 + c)*TT + txl)*64 + d*32 + q*8]) = ah;
    }
}

// ---------------------------------------------------------------------------
// Layer 1: same zero-LDS structure; x-projection is K=64 (2 chunks) over
// bf16 h1 rows (the h1-row loads ARE the B-frag layout, unchanged).
// ---------------------------------------------------------------------------
__global__ __launch_bounds__(64, 1) void gru_l1(
    const unsigned short* __restrict__ h1,   // (B,T,64) bf16
    const float* __restrict__ w_ih,   // (2,96,64)
    const float* __restrict__ w_hh,   // (2,96,32)
    const float* __restrict__ b_ih,   // (2,96)
    const float* __restrict__ b_hh,   // (2,96)
    unsigned short* __restrict__ out2) // (B,T,64) bf16
{
    const int tile = blockIdx.x;
    const int bt   = tile >> 1;
    const int d    = tile & 1;
    const int b0   = bt * 16;
    const int L    = threadIdx.x & 63;
    const int c    = L & 15;
    const int q    = L >> 4;

    short8 whh[3][2], wi0[3][2], wi1[3][2];
    #pragma unroll
    for (int g = 0; g < 3; ++g){
        const float sc = (g == 2) ? (2.0f * L2E) : L2E;
        #pragma unroll
        for (int gt = 0; gt < 2; ++gt){
            const int row = d*96 + g*32 + gt*16 + c;
            short8 f, g0, g1;
            #pragma unroll
            for (int j = 0; j < 8; ++j){
                f[j]  = f2bf(w_hh[(size_t)row*32 + q*8 + j] * sc);
                g0[j] = f2bf(w_ih[(size_t)row*64 +      q*8 + j] * sc);
                g1[j] = f2bf(w_ih[(size_t)row*64 + 32 + q*8 + j] * sc);
            }
            whh[g][gt] = f; wi0[g][gt] = g0; wi1[g][gt] = g1;
        }
    }
    floatx4 cbr[2], cbz[2], cbni[2], cbhn[2];
    #pragma unroll
    for (int gt = 0; gt < 2; ++gt){
        #pragma unroll
        for (int r = 0; r < 4; ++r){
            const int gidx = d*96 + gt*16 + q*4 + r;
            cbr[gt][r]  = L2E * (b_ih[gidx]      + b_hh[gidx]);
            cbz[gt][r]  = L2E * (b_ih[gidx + 32] + b_hh[gidx + 32]);
            cbni[gt][r] = 2.0f * L2E * b_ih[gidx + 64];
            cbhn[gt][r] = 2.0f * L2E * b_hh[gidx + 64];
        }
    }

    float hr[2][4] = {{0.f,0.f,0.f,0.f},{0.f,0.f,0.f,0.f}};
    short8 ah = {0,0,0,0,0,0,0,0};

    const int addrA = 4 * (c + 32 * (q & 1));
    const int addrB = addrA + 64;
    const bool selLo = (q < 2);

    const size_t arow = (size_t)(b0 + c) * TT;
    short8 a0c, a1c, a0n, a1n;
    {
        const int tx0 = d ? TT-1 : 0;
        a0c = *(const short8*)(&h1[(arow + tx0)*64 +      q*8]);
        a1c = *(const short8*)(&h1[(arow + tx0)*64 + 32 + q*8]);
        const int tx1 = d ? TT-2 : 1;
        a0n = *(const short8*)(&h1[(arow + tx1)*64 +      q*8]);
        a1n = *(const short8*)(&h1[(arow + tx1)*64 + 32 + q*8]);
    }

    #pragma unroll 2
    for (int t = 0; t < TT; ++t){
        floatx4 racc[2], zacc[2], xnacc[2], hnacc[2];
        // x-projection (register-prefetched h1 rows, no ah dependence)
        #pragma unroll
        for (int gt = 0; gt < 2; ++gt){
            racc[gt]  = __builtin_amdgcn_mfma_f32_16x16x32_bf16(wi0[0][gt], a0c, cbr[gt], 0, 0, 0);
            racc[gt]  = __builtin_amdgcn_mfma_f32_16x16x32_bf16(wi1[0][gt], a1c, racc[gt], 0, 0, 0);
            zacc[gt]  = __builtin_amdgcn_mfma_f32_16x16x32_bf16(wi0[1][gt], a0c, cbz[gt], 0, 0, 0);
            zacc[gt]  = __builtin_amdgcn_mfma_f32_16x16x32_bf16(wi1[1][gt], a1c, zacc[gt], 0, 0, 0);
            xnacc[gt] = __builtin_amdgcn_mfma_f32_16x16x32_bf16(wi0[2][gt], a0c, cbni[gt], 0, 0, 0);
            xnacc[gt] = __builtin_amdgcn_mfma_f32_16x16x32_bf16(wi1[2][gt], a1c, xnacc[gt], 0, 0, 0);
        }
        // h-side
        #pragma unroll
        for (int gt = 0; gt < 2; ++gt){
            racc[gt]  = __builtin_amdgcn_mfma_f32_16x16x32_bf16(whh[0][gt], ah, racc[gt], 0, 0, 0);
            zacc[gt]  = __builtin_amdgcn_mfma_f32_16x16x32_bf16(whh[1][gt], ah, zacc[gt], 0, 0, 0);
            hnacc[gt] = __builtin_amdgcn_mfma_f32_16x16x32_bf16(whh[2][gt], ah, cbhn[gt], 0, 0, 0);
        }

        if (t > 0){
            const int txp = d ? (TT - t) : (t - 1);
            *(short8*)(&out2[((size_t)(b0 + c)*TT + txp)*64 + d*32 + q*8]) = ah;
        }
        // prefetch h1 row for t+2
        short8 a02 = a0n, a12 = a1n;
        if (t + 2 < TT){
            const int tx2 = d ? (TT-3-t) : (t+2);
            a02 = *(const short8*)(&h1[(arow + tx2)*64 +      q*8]);
            a12 = *(const short8*)(&h1[(arow + tx2)*64 + 32 + q*8]);
        }

        #pragma unroll
        for (int gt = 0; gt < 2; ++gt){
            #pragma unroll
            for (int r = 0; r < 4; ++r){
                const float p  = 1.0f + exp2f_(-racc[gt][r]);
                const float qd = 1.0f + exp2f_(-zacc[gt][r]);
                const float s  = fast_rcp(p * qd);
                const float rg = s * qd;
                const float zg = s * p;
                const float e2 = exp2f_(xnacc[gt][r] + rg * hnacc[gt][r]);
                const float ng = 1.0f - 2.0f * fast_rcp(e2 + 1.0f);
                hr[gt][r] = ng + zg * (hr[gt][r] - ng);
            }
        }
        const int P0 = pack_bf(hr[0][0], hr[0][1]);
        const int P1 = pack_bf(hr[0][2], hr[0][3]);
        const int P2 = pack_bf(hr[1][0], hr[1][1]);
        const int P3 = pack_bf(hr[1][2], hr[1][3]);
        const int tA0 = __builtin_amdgcn_ds_bpermute(addrA, P0);
        const int tA1 = __builtin_amdgcn_ds_bpermute(addrA, P1);
        const int tA2 = __builtin_amdgcn_ds_bpermute(addrA, P2);
        const int tA3 = __builtin_amdgcn_ds_bpermute(addrA, P3);
        const int tB0 = __builtin_amdgcn_ds_bpermute(addrB, P0);
        const int tB1 = __builtin_amdgcn_ds_bpermute(addrB, P1);
        const int tB2 = __builtin_amdgcn_ds_bpermute(addrB, P2);
        const int tB3 = __builtin_amdgcn_ds_bpermute(addrB, P3);
        int4v R;
        R[0] = selLo ? tA0 : tA2;
        R[1] = selLo ? tA1 : tA3;
        R[2] = selLo ? tB0 : tB2;
        R[3] = selLo ? tB1 : tB3;
        ah = __builtin_bit_cast(short8, R);

        a0c = a0n; a1c = a1n; a0n = a02; a1n = a12;
    }
    {
        const int txl = d ? 0 : TT-1;
        *(short8*)(&out2[((size_t)(b0 + c)*TT + txl)*64 + d*32 + q*8]) = ah;
    }
}

// Attention pooling + FC + sigmoid (bf16 out2 input). One block per b.
__global__ __launch_bounds__(256) void attn_fc(
    const unsigned short* __restrict__ out2, // (B,T,64) bf16
    const float* __restrict__ attn_w, const float* __restrict__ attn_b,
    const float* __restrict__ fc_w,   const float* __restrict__ fc_b,
    float* __restrict__ out)
{
    const int b    = blockIdx.x;
    const int tid  = threadIdx.x;
    const int wave = tid >> 6;
    const int lane = tid & 63;

    __shared__ float logit_sh[TT];
    __shared__ float red_sh[4];
    __shared__ float ctx_sh[4][64];

    const float aw = attn_w[lane];
    const float ab = attn_b[0];

    for (int t = wave; t < TT; t += 4) {
        float v = bf2f(out2[((size_t)b*TT + t)*64 + lane]) * aw;
        #pragma unroll
        for (int off = 32; off > 0; off >>= 1) v += __shfl_xor(v, off, 64);
        if (lane == 0) logit_sh[t] = v + ab;
    }
    __syncthreads();

    float m = -INFINITY;
    for (int t = tid; t < TT; t += 256) m = fmaxf(m, logit_sh[t]);
    #pragma unroll
    for (int off = 32; off > 0; off >>= 1) m = fmaxf(m, __shfl_xor(m, off, 64));
    if (lane == 0) red_sh[wave] = m;
    __syncthreads();
    m = fmaxf(fmaxf(red_sh[0], red_sh[1]), fmaxf(red_sh[2], red_sh[3]));
    __syncthreads();
    float s = 0.0f;
    for (int t = tid; t < TT; t += 256) {
        const float e = __expf(logit_sh[t] - m);
        logit_sh[t] = e;
        s += e;
    }
    #pragma unroll
    for (int off = 32; off > 0; off >>= 1) s += __shfl_xor(s, off, 64);
    if (lane == 0) red_sh[wave] = s;
    __syncthreads();
    s = red_sh[0] + red_sh[1] + red_sh[2] + red_sh[3];
    const float inv_s = 1.0f / s;

    float acc = 0.0f;
    for (int t = wave; t < TT; t += 4)
        acc += logit_sh[t] * bf2f(out2[((size_t)b*TT + t)*64 + lane]);
    ctx_sh[wave][lane] = acc;
    __syncthreads();
    if (wave == 0) {
        const float c = (ctx_sh[0][lane] + ctx_sh[1][lane] +
                         ctx_sh[2][lane] + ctx_sh[3][lane]) * inv_s;
        float v = c * fc_w[lane];
        #pragma unroll
        for (int off = 32; off > 0; off >>= 1) v += __shfl_xor(v, off, 64);
        if (lane == 0) out[b] = sigmoidf_(v + fc_b[0]);
    }
}

extern "C" void kernel_launch(void* const* d_in, const int* in_sizes, int n_in,
                              void* d_out, int out_size, void* d_ws, size_t ws_size,
                              hipStream_t stream) {
    (void)in_sizes; (void)n_in; (void)out_size; (void)ws_size;
    const float* x      = (const float*)d_in[0];
    const float* w_ih0  = (const float*)d_in[1];
    const float* w_hh0  = (const float*)d_in[2];
    const float* b_ih0  = (const float*)d_in[3];
    const float* b_hh0  = (const float*)d_in[4];
    const float* w_ih1  = (const float*)d_in[5];
    const float* w_hh1  = (const float*)d_in[6];
    const float* b_ih1  = (const float*)d_in[7];
    const float* b_hh1  = (const float*)d_in[8];
    const float* attn_w = (const float*)d_in[9];
    const float* attn_b = (const float*)d_in[10];
    const float* fc_w   = (const float*)d_in[11];
    const float* fc_b   = (const float*)d_in[12];
    float* out = (float*)d_out;

    unsigned short* h1 = (unsigned short*)d_ws;                        // 67.1 MB bf16
    unsigned short* o2 = (unsigned short*)((char*)d_ws + 134217728);   // 67.1 MB bf16

    gru_l0<<<128, 64, 0, stream>>>(x, w_ih0, w_hh0, b_ih0, b_hh0, h1);
    gru_l1<<<128, 64, 0, stream>>>(h1, w_ih1, w_hh1, b_ih1, b_hh1, o2);
    attn_fc<<<BB, 256, 0, stream>>>(o2, attn_w, attn_b, fc_w, fc_b, out);
}

// Round 5
// 715.288 us; speedup vs baseline: 1.1573x; 1.1573x over previous
//
#include <hip/hip_runtime.h>
#include <math.h>

#define BB 1024
#define TT 512
#define L2E 1.4426950408889634f

typedef __attribute__((ext_vector_type(4))) short  bfx4;
typedef __attribute__((ext_vector_type(8))) short  bfx8;
typedef __attribute__((ext_vector_type(2))) int    int2v;
typedef __attribute__((ext_vector_type(4))) float  floatx4;

__device__ __forceinline__ float fast_rcp(float x){ return __builtin_amdgcn_rcpf(x); }
__device__ __forceinline__ float exp2f_(float x){ return __builtin_amdgcn_exp2f(x); }
__device__ __forceinline__ float sigmoidf_(float x){ return fast_rcp(1.0f + __expf(-x)); }
__device__ __forceinline__ unsigned short f2bf(float f){
    unsigned u = __builtin_bit_cast(unsigned, f);
    u += 0x7fffu + ((u >> 16) & 1u);
    return (unsigned short)(u >> 16);
}
__device__ __forceinline__ float bf2f(unsigned short u){
    return __builtin_bit_cast(float, ((unsigned)u) << 16);
}
// HW packed f32->bf16 (RNE), one instruction for two values
__device__ __forceinline__ int cvt_pk_bf16(float lo, float hi){
    int r; asm("v_cvt_pk_bf16_f32 %0, %1, %2" : "=v"(r) : "v"(lo), "v"(hi)); return r;
}
__device__ __forceinline__ floatx4 mfma16(bfx4 a, bfx4 b, floatx4 c){
    return __builtin_amdgcn_mfma_f32_16x16x16bf16_1k(a, b, c, 0, 0, 0);
}
__device__ __forceinline__ floatx4 mfma32(bfx8 a, bfx8 b, floatx4 c){
    return __builtin_amdgcn_mfma_f32_16x16x32_bf16(a, b, c, 0, 0, 0);
}

// ---------------------------------------------------------------------------
// Zero-shuffle biGRU recurrence via K=16 MFMA layout-matching.
// Swapped operands: D[i][b] = mfma(A = W-frag, B = h-frag).
// For 16x16x16: B-frag lane(c,q) holds k = q*4+j; D lane(c,q) reg r holds
// row = q*4+r, col = c. So the gate output elements (i = gt*16+q*4+r, b=c)
// sit in EXACTLY the lane that feeds them back as the next step's B operand
// (K=32 as two K=16 chunks: lo = gt0 regs, hi = gt1 regs). The whole
// h_t -> B-frag repack is 4 in-lane v_cvt_pk_bf16_f32. No LDS, no shuffles,
// no barriers anywhere on the recurrence chain.
// Biases ride in the MFMA C operand; weights prescaled by log2e (r,z) /
// 2*log2e (n) so gates use raw v_exp (exp2) with free neg modifiers.
// h store: per-step in-lane 2x dwordx2 (fire-and-forget, off-chain).
// ---------------------------------------------------------------------------
__global__ __launch_bounds__(64, 1) void gru_l0(
    const float* __restrict__ x,      // (B,T,4) f32
    const float* __restrict__ w_ih,   // (2,96,4)
    const float* __restrict__ w_hh,   // (2,96,32)
    const float* __restrict__ b_ih,   // (2,96)
    const float* __restrict__ b_hh,   // (2,96)
    unsigned short* __restrict__ h1)  // (B,T,64) bf16
{
    const int tile = blockIdx.x;      // 0..127
    const int bt   = tile >> 1;
    const int d    = tile & 1;
    const int b0   = bt * 16;
    const int L    = threadIdx.x & 63;
    const int c    = L & 15;
    const int q    = L >> 4;

    // K16 A-frags of W_hh: whh[g][gt][kc], lane(c,q) = W[g*32+gt*16+c][kc*16+q*4+j]
    bfx4 whh[3][2][2];
    bfx4 wih[3][2];
    #pragma unroll
    for (int g = 0; g < 3; ++g){
        const float sc = (g == 2) ? (2.0f * L2E) : L2E;
        #pragma unroll
        for (int gt = 0; gt < 2; ++gt){
            const int row = d*96 + g*32 + gt*16 + c;
            #pragma unroll
            for (int kc = 0; kc < 2; ++kc){
                bfx4 f;
                #pragma unroll
                for (int j = 0; j < 4; ++j)
                    f[j] = f2bf(w_hh[(size_t)row*32 + kc*16 + q*4 + j] * sc);
                whh[g][gt][kc] = f;
            }
            bfx4 fi = {0,0,0,0};
            if (q == 0){
                #pragma unroll
                for (int j = 0; j < 4; ++j) fi[j] = f2bf(w_ih[(size_t)row*4 + j] * sc);
            }
            wih[g][gt] = fi;
        }
    }
    // biases as per-reg C vectors: reg r of gtile gt sits at i = gt*16 + q*4 + r
    floatx4 cbr[2], cbz[2], cbni[2], cbhn[2];
    #pragma unroll
    for (int gt = 0; gt < 2; ++gt){
        #pragma unroll
        for (int r = 0; r < 4; ++r){
            const int gidx = d*96 + gt*16 + q*4 + r;
            cbr[gt][r]  = L2E * (b_ih[gidx]      + b_hh[gidx]);
            cbz[gt][r]  = L2E * (b_ih[gidx + 32] + b_hh[gidx + 32]);
            cbni[gt][r] = 2.0f * L2E * b_ih[gidx + 64];
            cbhn[gt][r] = 2.0f * L2E * b_hh[gidx + 64];
        }
    }

    float hr[2][4] = {{0.f,0.f,0.f,0.f},{0.f,0.f,0.f,0.f}};
    bfx4 ahlo = {0,0,0,0}, ahhi = {0,0,0,0};   // h_{-1} = 0 as two K16 B-frags

    const size_t xrow = (size_t)(b0 + c) * TT;
    float4 xc = {0,0,0,0}, xn1 = {0,0,0,0};
    if (q == 0){
        xc  = *(const float4*)(x + (xrow + (d ? TT-1 : 0))*4);
        xn1 = *(const float4*)(x + (xrow + (d ? TT-2 : 1))*4);
    }

    for (int t = 0; t < TT; ++t){
        bfx4 ax = {0,0,0,0};
        if (q == 0){
            int2v a; a[0] = cvt_pk_bf16(xc.x, xc.y); a[1] = cvt_pk_bf16(xc.z, xc.w);
            ax = __builtin_bit_cast(bfx4, a);
        }

        floatx4 racc[2], zacc[2], xnacc[2], hnacc[2];
        // x-side (off-chain: ax from register prefetch)
        #pragma unroll
        for (int gt = 0; gt < 2; ++gt){
            racc[gt]  = mfma16(wih[0][gt], ax, cbr[gt]);
            zacc[gt]  = mfma16(wih[1][gt], ax, cbz[gt]);
            xnacc[gt] = mfma16(wih[2][gt], ax, cbni[gt]);
        }
        // h-side (on-chain): two chained K16 chunks consume ahlo/ahhi
        #pragma unroll
        for (int gt = 0; gt < 2; ++gt){
            racc[gt]  = mfma16(whh[0][gt][0], ahlo, racc[gt]);
            racc[gt]  = mfma16(whh[0][gt][1], ahhi, racc[gt]);
            zacc[gt]  = mfma16(whh[1][gt][0], ahlo, zacc[gt]);
            zacc[gt]  = mfma16(whh[1][gt][1], ahhi, zacc[gt]);
            hnacc[gt] = mfma16(whh[2][gt][0], ahlo, cbhn[gt]);
            hnacc[gt] = mfma16(whh[2][gt][1], ahhi, hnacc[gt]);
        }

        // prefetch x for t+2 (off-chain)
        float4 xn2 = xn1;
        if (q == 0 && t + 2 < TT)
            xn2 = *(const float4*)(x + (xrow + (d ? TT-3-t : t+2))*4);

        // gates: lane(c,q) reg(gt,r) -> b=c, i = gt*16 + q*4 + r
        #pragma unroll
        for (int gt = 0; gt < 2; ++gt){
            #pragma unroll
            for (int r = 0; r < 4; ++r){
                const float p  = 1.0f + exp2f_(-racc[gt][r]);
                const float qd = 1.0f + exp2f_(-zacc[gt][r]);
                const float s  = fast_rcp(p * qd);
                const float rg = s * qd;
                const float zg = s * p;
                const float e2 = exp2f_(xnacc[gt][r] + rg * hnacc[gt][r]);
                const float ng = 1.0f - 2.0f * fast_rcp(e2 + 1.0f);
                hr[gt][r] = ng + zg * (hr[gt][r] - ng);
            }
        }
        // in-lane repack: D regs ARE the next B-frag elements
        int2v plo, phi;
        plo[0] = cvt_pk_bf16(hr[0][0], hr[0][1]);
        plo[1] = cvt_pk_bf16(hr[0][2], hr[0][3]);
        phi[0] = cvt_pk_bf16(hr[1][0], hr[1][1]);
        phi[1] = cvt_pk_bf16(hr[1][2], hr[1][3]);
        ahlo = __builtin_bit_cast(bfx4, plo);
        ahhi = __builtin_bit_cast(bfx4, phi);

        // store h_t (fire-and-forget, off-chain): two 8B runs per lane
        const int tx = d ? (TT-1-t) : t;
        unsigned short* hp = &h1[((size_t)(b0 + c)*TT + tx)*64 + d*32 + q*4];
        *(int2v*)(hp)      = plo;   // i = q*4 .. q*4+3
        *(int2v*)(hp + 16) = phi;   // i = 16+q*4 .. 16+q*4+3

        xc = xn1; xn1 = xn2;
    }
}

// ---------------------------------------------------------------------------
// Layer 1: same zero-shuffle structure; x-projection is K=64 over bf16 h1
// rows as two K32 MFMAs (register-prefetched, off-chain); h-side recurrence
// as chained K16 pairs feeding straight from the previous step's D regs.
// ---------------------------------------------------------------------------
__global__ __launch_bounds__(64, 1) void gru_l1(
    const unsigned short* __restrict__ h1,   // (B,T,64) bf16
    const float* __restrict__ w_ih,   // (2,96,64)
    const float* __restrict__ w_hh,   // (2,96,32)
    const float* __restrict__ b_ih,   // (2,96)
    const float* __restrict__ b_hh,   // (2,96)
    unsigned short* __restrict__ out2) // (B,T,64) bf16
{
    const int tile = blockIdx.x;
    const int bt   = tile >> 1;
    const int d    = tile & 1;
    const int b0   = bt * 16;
    const int L    = threadIdx.x & 63;
    const int c    = L & 15;
    const int q    = L >> 4;

    bfx4 whh[3][2][2];
    bfx8 wi0[3][2], wi1[3][2];
    #pragma unroll
    for (int g = 0; g < 3; ++g){
        const float sc = (g == 2) ? (2.0f * L2E) : L2E;
        #pragma unroll
        for (int gt = 0; gt < 2; ++gt){
            const int row = d*96 + g*32 + gt*16 + c;
            #pragma unroll
            for (int kc = 0; kc < 2; ++kc){
                bfx4 f;
                #pragma unroll
                for (int j = 0; j < 4; ++j)
                    f[j] = f2bf(w_hh[(size_t)row*32 + kc*16 + q*4 + j] * sc);
                whh[g][gt][kc] = f;
            }
            bfx8 g0, g1;
            #pragma unroll
            for (int j = 0; j < 8; ++j){
                g0[j] = f2bf(w_ih[(size_t)row*64 +      q*8 + j] * sc);
                g1[j] = f2bf(w_ih[(size_t)row*64 + 32 + q*8 + j] * sc);
            }
            wi0[g][gt] = g0; wi1[g][gt] = g1;
        }
    }
    floatx4 cbr[2], cbz[2], cbni[2], cbhn[2];
    #pragma unroll
    for (int gt = 0; gt < 2; ++gt){
        #pragma unroll
        for (int r = 0; r < 4; ++r){
            const int gidx = d*96 + gt*16 + q*4 + r;
            cbr[gt][r]  = L2E * (b_ih[gidx]      + b_hh[gidx]);
            cbz[gt][r]  = L2E * (b_ih[gidx + 32] + b_hh[gidx + 32]);
            cbni[gt][r] = 2.0f * L2E * b_ih[gidx + 64];
            cbhn[gt][r] = 2.0f * L2E * b_hh[gidx + 64];
        }
    }

    float hr[2][4] = {{0.f,0.f,0.f,0.f},{0.f,0.f,0.f,0.f}};
    bfx4 ahlo = {0,0,0,0}, ahhi = {0,0,0,0};

    const size_t arow = (size_t)(b0 + c) * TT;
    bfx8 a0c, a1c, a0n, a1n;
    {
        const int tx0 = d ? TT-1 : 0;
        a0c = *(const bfx8*)(&h1[(arow + tx0)*64 +      q*8]);
        a1c = *(const bfx8*)(&h1[(arow + tx0)*64 + 32 + q*8]);
        const int tx1 = d ? TT-2 : 1;
        a0n = *(const bfx8*)(&h1[(arow + tx1)*64 +      q*8]);
        a1n = *(const bfx8*)(&h1[(arow + tx1)*64 + 32 + q*8]);
    }

    for (int t = 0; t < TT; ++t){
        floatx4 racc[2], zacc[2], xnacc[2], hnacc[2];
        // x-projection K=64 as two K32 chunks (off-chain, register-prefetched)
        #pragma unroll
        for (int gt = 0; gt < 2; ++gt){
            racc[gt]  = mfma32(wi0[0][gt], a0c, cbr[gt]);
            racc[gt]  = mfma32(wi1[0][gt], a1c, racc[gt]);
            zacc[gt]  = mfma32(wi0[1][gt], a0c, cbz[gt]);
            zacc[gt]  = mfma32(wi1[1][gt], a1c, zacc[gt]);
            xnacc[gt] = mfma32(wi0[2][gt], a0c, cbni[gt]);
            xnacc[gt] = mfma32(wi1[2][gt], a1c, xnacc[gt]);
        }
        // h-side (on-chain) K16 chained pairs
        #pragma unroll
        for (int gt = 0; gt < 2; ++gt){
            racc[gt]  = mfma16(whh[0][gt][0], ahlo, racc[gt]);
            racc[gt]  = mfma16(whh[0][gt][1], ahhi, racc[gt]);
            zacc[gt]  = mfma16(whh[1][gt][0], ahlo, zacc[gt]);
            zacc[gt]  = mfma16(whh[1][gt][1], ahhi, zacc[gt]);
            hnacc[gt] = mfma16(whh[2][gt][0], ahlo, cbhn[gt]);
            hnacc[gt] = mfma16(whh[2][gt][1], ahhi, hnacc[gt]);
        }

        // prefetch h1 row for t+2 (off-chain)
        bfx8 a02 = a0n, a12 = a1n;
        if (t + 2 < TT){
            const int tx2 = d ? (TT-3-t) : (t+2);
            a02 = *(const bfx8*)(&h1[(arow + tx2)*64 +      q*8]);
            a12 = *(const bfx8*)(&h1[(arow + tx2)*64 + 32 + q*8]);
        }

        #pragma unroll
        for (int gt = 0; gt < 2; ++gt){
            #pragma unroll
            for (int r = 0; r < 4; ++r){
                const float p  = 1.0f + exp2f_(-racc[gt][r]);
                const float qd = 1.0f + exp2f_(-zacc[gt][r]);
                const float s  = fast_rcp(p * qd);
                const float rg = s * qd;
                const float zg = s * p;
                const float e2 = exp2f_(xnacc[gt][r] + rg * hnacc[gt][r]);
                const float ng = 1.0f - 2.0f * fast_rcp(e2 + 1.0f);
                hr[gt][r] = ng + zg * (hr[gt][r] - ng);
            }
        }
        int2v plo, phi;
        plo[0] = cvt_pk_bf16(hr[0][0], hr[0][1]);
        plo[1] = cvt_pk_bf16(hr[0][2], hr[0][3]);
        phi[0] = cvt_pk_bf16(hr[1][0], hr[1][1]);
        phi[1] = cvt_pk_bf16(hr[1][2], hr[1][3]);
        ahlo = __builtin_bit_cast(bfx4, plo);
        ahhi = __builtin_bit_cast(bfx4, phi);

        const int tx = d ? (TT-1-t) : t;
        unsigned short* op = &out2[((size_t)(b0 + c)*TT + tx)*64 + d*32 + q*4];
        *(int2v*)(op)      = plo;
        *(int2v*)(op + 16) = phi;

        a0c = a0n; a1c = a1n; a0n = a02; a1n = a12;
    }
}

// Attention pooling + FC + sigmoid (bf16 out2 input). One block per b.
__global__ __launch_bounds__(256) void attn_fc(
    const unsigned short* __restrict__ out2, // (B,T,64) bf16
    const float* __restrict__ attn_w, const float* __restrict__ attn_b,
    const float* __restrict__ fc_w,   const float* __restrict__ fc_b,
    float* __restrict__ out)
{
    const int b    = blockIdx.x;
    const int tid  = threadIdx.x;
    const int wave = tid >> 6;
    const int lane = tid & 63;

    __shared__ float logit_sh[TT];
    __shared__ float red_sh[4];
    __shared__ float ctx_sh[4][64];

    const float aw = attn_w[lane];
    const float ab = attn_b[0];

    for (int t = wave; t < TT; t += 4) {
        float v = bf2f(out2[((size_t)b*TT + t)*64 + lane]) * aw;
        #pragma unroll
        for (int off = 32; off > 0; off >>= 1) v += __shfl_xor(v, off, 64);
        if (lane == 0) logit_sh[t] = v + ab;
    }
    __syncthreads();

    float m = -INFINITY;
    for (int t = tid; t < TT; t += 256) m = fmaxf(m, logit_sh[t]);
    #pragma unroll
    for (int off = 32; off > 0; off >>= 1) m = fmaxf(m, __shfl_xor(m, off, 64));
    if (lane == 0) red_sh[wave] = m;
    __syncthreads();
    m = fmaxf(fmaxf(red_sh[0], red_sh[1]), fmaxf(red_sh[2], red_sh[3]));
    __syncthreads();
    float s = 0.0f;
    for (int t = tid; t < TT; t += 256) {
        const float e = __expf(logit_sh[t] - m);
        logit_sh[t] = e;
        s += e;
    }
    #pragma unroll
    for (int off = 32; off > 0; off >>= 1) s += __shfl_xor(s, off, 64);
    if (lane == 0) red_sh[wave] = s;
    __syncthreads();
    s = red_sh[0] + red_sh[1] + red_sh[2] + red_sh[3];
    const float inv_s = 1.0f / s;

    float acc = 0.0f;
    for (int t = wave; t < TT; t += 4)
        acc += logit_sh[t] * bf2f(out2[((size_t)b*TT + t)*64 + lane]);
    ctx_sh[wave][lane] = acc;
    __syncthreads();
    if (wave == 0) {
        const float c = (ctx_sh[0][lane] + ctx_sh[1][lane] +
                         ctx_sh[2][lane] + ctx_sh[3][lane]) * inv_s;
        float v = c * fc_w[lane];
        #pragma unroll
        for (int off = 32; off > 0; off >>= 1) v += __shfl_xor(v, off, 64);
        if (lane == 0) out[b] = sigmoidf_(v + fc_b[0]);
    }
}

extern "C" void kernel_launch(void* const* d_in, const int* in_sizes, int n_in,
                              void* d_out, int out_size, void* d_ws, size_t ws_size,
                              hipStream_t stream) {
    (void)in_sizes; (void)n_in; (void)out_size; (void)ws_size;
    const float* x      = (const float*)d_in[0];
    const float* w_ih0  = (const float*)d_in[1];
    const float* w_hh0  = (const float*)d_in[2];
    const float* b_ih0  = (const float*)d_in[3];
    const float* b_hh0  = (const float*)d_in[4];
    const float* w_ih1  = (const float*)d_in[5];
    const float* w_hh1  = (const float*)d_in[6];
    const float* b_ih1  = (const float*)d_in[7];
    const float* b_hh1  = (const float*)d_in[8];
    const float* attn_w = (const float*)d_in[9];
    const float* attn_b = (const float*)d_in[10];
    const float* fc_w   = (const float*)d_in[11];
    const float* fc_b   = (const float*)d_in[12];
    float* out = (float*)d_out;

    unsigned short* h1 = (unsigned short*)d_ws;                        // 67.1 MB bf16
    unsigned short* o2 = (unsigned short*)((char*)d_ws + 134217728);   // 67.1 MB bf16

    gru_l0<<<128, 64, 0, stream>>>(x, w_ih0, w_hh0, b_ih0, b_hh0, h1);
    gru_l1<<<128, 64, 0, stream>>>(h1, w_ih1, w_hh1, b_ih1, b_hh1, o2);
    attn_fc<<<BB, 256, 0, stream>>>(o2, attn_w, attn_b, fc_w, fc_b, out);
}